// Round 18
// baseline (157.600 us; speedup 1.0000x reference)
//
#include <hip/hip_runtime.h>
#include <hip/hip_bf16.h>
#include <stdint.h>

// MultiHeadAttention fused forward, MI355X/gfx950.
// B=4, S=2048, H=16, hd=64, D=1024. fp32 in/out, bf16 MFMA internally.

typedef __attribute__((ext_vector_type(8))) __bf16 bf16x8;
typedef __attribute__((ext_vector_type(4))) float f32x4;
typedef __attribute__((ext_vector_type(16))) float f32x16;

#define AS_G __attribute__((address_space(1)))
#define AS_L __attribute__((address_space(3)))

__device__ __forceinline__ void gload_lds16(const void* g, void* s) {
  __builtin_amdgcn_global_load_lds((const AS_G void*)g, (AS_L void*)s, 16, 0, 0);
}

__device__ __forceinline__ unsigned cvt_pk_bf16(float lo, float hi) {
  unsigned r;
  asm("v_cvt_pk_bf16_f32 %0, %1, %2" : "=v"(r) : "v"(lo), "v"(hi));
  return r;
}

// ---------------------------------------------------------------- fused cvt
// One launch: blocks [0,4096) x->bf16 ; [4096,7168) Wqkv^T ; [7168,8192) Wo^T
__device__ __forceinline__ void cvt_T_body(const float* __restrict__ in,
                                           __bf16* __restrict__ out,
                                           int K, int N, int bx, int by,
                                           float (*tile)[33]) {
  int tx = threadIdx.x & 31, ty = threadIdx.x >> 5;  // 32 x 8
#pragma unroll
  for (int i = 0; i < 32; i += 8)
    tile[ty + i][tx] = in[(size_t)(by * 32 + ty + i) * N + bx * 32 + tx];
  __syncthreads();
#pragma unroll
  for (int i = 0; i < 32; i += 8)
    out[(size_t)(bx * 32 + ty + i) * K + by * 32 + tx] = (__bf16)tile[tx][ty + i];
}

__global__ void fused_cvt_kernel(const float* __restrict__ x,
                                 __bf16* __restrict__ xb,
                                 const float* __restrict__ Wqkv,
                                 __bf16* __restrict__ Wqt,
                                 const float* __restrict__ Wo,
                                 __bf16* __restrict__ Wot) {
  __shared__ float tile[32][33];
  const int bid = blockIdx.x;
  if (bid < 4096) {
    const int i = bid * 256 + threadIdx.x;  // n8 = 1048576
    float4 a = ((const float4*)x)[i * 2];
    float4 b = ((const float4*)x)[i * 2 + 1];
    union { __bf16 h[8]; int4 v; } u;
    u.h[0] = (__bf16)a.x; u.h[1] = (__bf16)a.y; u.h[2] = (__bf16)a.z; u.h[3] = (__bf16)a.w;
    u.h[4] = (__bf16)b.x; u.h[5] = (__bf16)b.y; u.h[6] = (__bf16)b.z; u.h[7] = (__bf16)b.w;
    ((int4*)xb)[i] = u.v;
  } else if (bid < 7168) {
    const int t = bid - 4096;               // 96 x 32
    cvt_T_body(Wqkv, Wqt, 1024, 3072, t % 96, t / 96, tile);
  } else {
    const int t = bid - 7168;               // 32 x 32
    cvt_T_body(Wo, Wot, 1024, 1024, t % 32, t / 32, tile);
  }
}

// ---------------------------------------------------------------- GEMM 256x128
// R14/R16 structure (proven 63.3us): single barrier per phase, 3-buffer
// rotation, 2 blocks/CU. BM=256, BN=128, K-chunk=32, 8 waves (4M x 2N).
// LDS 72KB: A 3x16KB @0, B 3x8KB @49152. QKV scatter epilogue, grid 768.
__global__ __launch_bounds__(512, 4) void gemm_qkv(
    const __bf16* __restrict__ A, const __bf16* __restrict__ Bt,
    const float* __restrict__ bias,
    __bf16* __restrict__ Qb, __bf16* __restrict__ Kb, __bf16* __restrict__ Vtb) {
  __shared__ char lds[73728];   // A: 3 x 16KB @0, B: 3 x 8KB @49152
  const int tid = threadIdx.x;
  const int wv = tid >> 6, lane = tid & 63;
  const int lhi = lane >> 4, llo = lane & 15;
  const int wm = wv >> 1, wn = wv & 1;   // 4M x 2N

  const int wg = blockIdx.x;
  const int xcd = wg & 7, local = wg >> 3;
  const int m0 = (xcd * 4 + (local & 3)) * 256;
  const int n0 = (local >> 2) * 128;

  int SA[2], SB;
#pragma unroll
  for (int j = 0; j < 2; ++j) {
    const int idx = j * 512 + tid;
    const int v = idx >> 3, wl = idx & 7;
    const int wg_ = wl ^ (v & 7);
    SA[j] = ((v << 1) | (wg_ >> 2)) * 1024 + (wg_ & 3) * 8;
  }
  {
    const int v = tid >> 3, wl = tid & 7;
    const int wg_ = wl ^ (v & 7);
    SB = ((v << 1) | (wg_ >> 2)) * 1024 + (wg_ & 3) * 8;
  }
  const __bf16* Asrc = A + (size_t)m0 * 1024;
  const __bf16* Bsrc = Bt + (size_t)n0 * 1024;
  const int wvb = wv * 1024;

#define STAGE_R(b, kc)                                                      \
  gload_lds16(Asrc + SA[0] + (kc) * 32, &lds[(b) * 16384 + wvb]);           \
  gload_lds16(Asrc + SA[1] + (kc) * 32, &lds[(b) * 16384 + 8192 + wvb]);    \
  gload_lds16(Bsrc + SB + (kc) * 32,    &lds[49152 + (b) * 8192 + wvb]);

  f32x4 acc[4][4];
#pragma unroll
  for (int mi = 0; mi < 4; ++mi)
#pragma unroll
    for (int nj = 0; nj < 4; ++nj) acc[mi][nj] = (f32x4){0.f, 0.f, 0.f, 0.f};

  auto aoff = [&](int b, int f) {
    const int r = wm * 64 + f * 16 + llo;
    const int v = r >> 1;
    const int w = ((r & 1) << 2) | lhi;
    return b * 16384 + v * 128 + ((w ^ (v & 7)) << 4);
  };
  auto boff = [&](int b, int f2) {
    const int r = wn * 64 + f2 * 16 + llo;
    const int v = r >> 1;
    const int w = ((r & 1) << 2) | lhi;
    return 49152 + b * 8192 + v * 128 + ((w ^ (v & 7)) << 4);
  };

  auto PH = [&](int c, int sb, int kc) {
    __builtin_amdgcn_s_barrier();
    __builtin_amdgcn_sched_barrier(0);
    bf16x8 fa[4], fb[4];
#pragma unroll
    for (int f = 0; f < 4; ++f) fa[f] = *(const bf16x8*)&lds[aoff(c, f)];
#pragma unroll
    for (int f2 = 0; f2 < 4; ++f2) fb[f2] = *(const bf16x8*)&lds[boff(c, f2)];
    STAGE_R(sb, kc);
    __builtin_amdgcn_sched_barrier(0);
    asm volatile("s_waitcnt lgkmcnt(0)" ::: "memory");
    __builtin_amdgcn_sched_barrier(0);
    __builtin_amdgcn_s_setprio(1);
#pragma unroll
    for (int mi = 0; mi < 4; ++mi)
#pragma unroll
      for (int nj = 0; nj < 4; ++nj)
        acc[mi][nj] = __builtin_amdgcn_mfma_f32_16x16x32_bf16(fa[mi], fb[nj],
                                                              acc[mi][nj], 0, 0, 0);
    __builtin_amdgcn_s_setprio(0);
    __builtin_amdgcn_sched_barrier(0);
    asm volatile("s_waitcnt vmcnt(3)" ::: "memory");
  };

  STAGE_R(0, 0);
  STAGE_R(1, 1);
  __builtin_amdgcn_sched_barrier(0);
  asm volatile("s_waitcnt vmcnt(3)" ::: "memory");

  {
    int c = 0, sb = 2;
    for (int p = 0; p < 32; ++p) {
      const int kc = (p + 2) & 31;
      PH(c, sb, kc);
      if (++c == 3) c = 0;
      if (++sb == 3) sb = 0;
    }
  }
#undef STAGE_R

#pragma unroll
  for (int nj = 0; nj < 4; ++nj) {
    const int col = n0 + wn * 64 + nj * 16 + llo;
    const float bv = bias[col];
    const int h = col / 192, rem = col % 192;
#pragma unroll
    for (int mi = 0; mi < 4; ++mi) {
      const int row0 = m0 + wm * 64 + mi * 16 + lhi * 4;
      const int b = row0 >> 11;
      const int s0 = row0 & 2047;
      const int bh = b * 16 + h;
      f32x4 v = acc[mi][nj];
      if (rem < 64) {
        // Q pre-scaled by (1/sqrt(64)) * log2(e) for exp2-domain softmax
#pragma unroll
        for (int r = 0; r < 4; ++r)
          Qb[((size_t)bh * 2048 + s0 + r) * 64 + rem] =
              (__bf16)((v[r] + bv) * 0.18033688011112042f);
      } else if (rem < 128) {
#pragma unroll
        for (int r = 0; r < 4; ++r)
          Kb[((size_t)bh * 2048 + s0 + r) * 64 + (rem - 64)] = (__bf16)(v[r] + bv);
      } else {
        union { __bf16 h4[4]; int2 v2; } uq;
#pragma unroll
        for (int r = 0; r < 4; ++r) uq.h4[r] = (__bf16)(v[r] + bv);
        *(int2*)&Vtb[((size_t)bh * 64 + (rem - 128)) * 2048 + s0] = uq.v2;
      }
    }
  }
}

// ---------------------------------------------------------------- GEMM 256x64
// Output projection: same phase/ledger/swizzle, BN=64 -> LDS 60KB, grid 512
// (32m x 16n) = exactly 2 blocks/CU, one round. Waves 4M x 2N of 64x32.
// B chunk = 4KB; all 8 waves issue 1 B gload, waves w and w+4 duplicate-write
// identical bytes (benign; keeps vmcnt wave-uniform at 3/phase).
__global__ __launch_bounds__(512, 4) void gemm_o(
    const __bf16* __restrict__ A, const __bf16* __restrict__ Bt,
    const float* __restrict__ bias, float* __restrict__ Out) {
  __shared__ char lds[61440];   // A: 3 x 16KB @0, B: 3 x 4KB @49152
  const int tid = threadIdx.x;
  const int wv = tid >> 6, lane = tid & 63;
  const int lhi = lane >> 4, llo = lane & 15;
  const int wm = wv >> 1, wn = wv & 1;   // 4M x 2N (wave 64x32)

  const int wg = blockIdx.x;              // grid 512, % 8 == 0
  const int xcd = wg & 7, local = wg >> 3;  // local 0..63
  const int m0 = (xcd * 4 + (local & 3)) * 256;
  const int n0 = (local >> 2) * 64;

  int SA[2], SB;
#pragma unroll
  for (int j = 0; j < 2; ++j) {
    const int idx = j * 512 + tid;
    const int v = idx >> 3, wl = idx & 7;
    const int wg_ = wl ^ (v & 7);
    SA[j] = ((v << 1) | (wg_ >> 2)) * 1024 + (wg_ & 3) * 8;
  }
  {
    const int idx = tid & 255;            // waves 0-3 / 4-7 duplicate
    const int v = idx >> 3, wl = idx & 7;
    const int wg_ = wl ^ (v & 7);
    SB = ((v << 1) | (wg_ >> 2)) * 1024 + (wg_ & 3) * 8;
  }
  const __bf16* Asrc = A + (size_t)m0 * 1024;
  const __bf16* Bsrc = Bt + (size_t)n0 * 1024;
  const int wvb = wv * 1024;
  const int wvb4 = (wv & 3) * 1024;       // B dest within 4KB chunk

#define STAGE_R(b, kc)                                                      \
  gload_lds16(Asrc + SA[0] + (kc) * 32, &lds[(b) * 16384 + wvb]);           \
  gload_lds16(Asrc + SA[1] + (kc) * 32, &lds[(b) * 16384 + 8192 + wvb]);    \
  gload_lds16(Bsrc + SB + (kc) * 32,    &lds[49152 + (b) * 4096 + wvb4]);

  f32x4 acc[4][2];
#pragma unroll
  for (int mi = 0; mi < 4; ++mi)
#pragma unroll
    for (int nj = 0; nj < 2; ++nj) acc[mi][nj] = (f32x4){0.f, 0.f, 0.f, 0.f};

  auto aoff = [&](int b, int f) {
    const int r = wm * 64 + f * 16 + llo;
    const int v = r >> 1;
    const int w = ((r & 1) << 2) | lhi;
    return b * 16384 + v * 128 + ((w ^ (v & 7)) << 4);
  };
  auto boff = [&](int b, int f2) {
    const int r = wn * 32 + f2 * 16 + llo;
    const int v = r >> 1;
    const int w = ((r & 1) << 2) | lhi;
    return 49152 + b * 4096 + v * 128 + ((w ^ (v & 7)) << 4);
  };

  auto PH = [&](int c, int sb, int kc) {
    __builtin_amdgcn_s_barrier();
    __builtin_amdgcn_sched_barrier(0);
    bf16x8 fa[4], fb[2];
#pragma unroll
    for (int f = 0; f < 4; ++f) fa[f] = *(const bf16x8*)&lds[aoff(c, f)];
#pragma unroll
    for (int f2 = 0; f2 < 2; ++f2) fb[f2] = *(const bf16x8*)&lds[boff(c, f2)];
    STAGE_R(sb, kc);
    __builtin_amdgcn_sched_barrier(0);
    asm volatile("s_waitcnt lgkmcnt(0)" ::: "memory");
    __builtin_amdgcn_sched_barrier(0);
    __builtin_amdgcn_s_setprio(1);
#pragma unroll
    for (int mi = 0; mi < 4; ++mi)
#pragma unroll
      for (int nj = 0; nj < 2; ++nj)
        acc[mi][nj] = __builtin_amdgcn_mfma_f32_16x16x32_bf16(fa[mi], fb[nj],
                                                              acc[mi][nj], 0, 0, 0);
    __builtin_amdgcn_s_setprio(0);
    __builtin_amdgcn_sched_barrier(0);
    asm volatile("s_waitcnt vmcnt(3)" ::: "memory");
  };

  STAGE_R(0, 0);
  STAGE_R(1, 1);
  __builtin_amdgcn_sched_barrier(0);
  asm volatile("s_waitcnt vmcnt(3)" ::: "memory");

  {
    int c = 0, sb = 2;
    for (int p = 0; p < 32; ++p) {
      const int kc = (p + 2) & 31;
      PH(c, sb, kc);
      if (++c == 3) c = 0;
      if (++sb == 3) sb = 0;
    }
  }
#undef STAGE_R

#pragma unroll
  for (int nj = 0; nj < 2; ++nj) {
    const int col = n0 + wn * 32 + nj * 16 + llo;
    const float bv = bias[col];
#pragma unroll
    for (int mi = 0; mi < 4; ++mi) {
      const int row0 = m0 + wm * 64 + mi * 16 + lhi * 4;
      f32x4 v = acc[mi][nj];
#pragma unroll
      for (int r = 0; r < 4; ++r)
        Out[(size_t)(row0 + r) * 1024 + col] = v[r] + bv;
    }
  }
}

// ---------------------------------------------------------------- attention
// 4 waves x 32 q-rows = 128-row chunk per block; 1024 blocks (4/CU).
// Swapped QK^T / swapped PV; NO-MAX exp2 softmax (bounded logits; exact by
// shift invariance). zz as QK MFMA C-operand. l accumulated via MFMA with a
// ones A-operand (row-independent D; lane's col = its q-row -> l = accl[0]).

__device__ __forceinline__ void attn_tile(
    const __bf16* __restrict__ ksb, const __bf16* __restrict__ vsb,
    const bf16x8* qf, const f32x16& zz, const bf16x8& ones,
    int kv0, int q0w, int lq, int hi,
    f32x16& o0, f32x16& o1, f32x16& accl) {
  const int r0 = lq, r1 = 32 + lq;
  const int fx = (lq & 7) ^ ((lq >> 3) << 1);  // matches staging swizzle
  f32x16 s0, s1;
  __builtin_amdgcn_s_setprio(1);
  {
    const int bb = (hi ^ fx) * 8;
    bf16x8 k0 = *(const bf16x8*)&ksb[r0 * 64 + bb];
    bf16x8 k1 = *(const bf16x8*)&ksb[r1 * 64 + bb];
    s0 = __builtin_amdgcn_mfma_f32_32x32x16_bf16(k0, qf[0], zz, 0, 0, 0);
    s1 = __builtin_amdgcn_mfma_f32_32x32x16_bf16(k1, qf[0], zz, 0, 0, 0);
  }
#pragma unroll
  for (int ds = 1; ds < 4; ++ds) {
    const int bb = ((ds * 2 + hi) ^ fx) * 8;
    bf16x8 k0 = *(const bf16x8*)&ksb[r0 * 64 + bb];
    bf16x8 k1 = *(const bf16x8*)&ksb[r1 * 64 + bb];
    s0 = __builtin_amdgcn_mfma_f32_32x32x16_bf16(k0, qf[ds], s0, 0, 0, 0);
    s1 = __builtin_amdgcn_mfma_f32_32x32x16_bf16(k1, qf[ds], s1, 0, 0, 0);
  }
  __builtin_amdgcn_s_setprio(0);

  const int qg = q0w + lq;
  if (kv0 + 63 > q0w) {  // causal mask (log2 domain; -1e30 -> exp2 = 0)
#pragma unroll
    for (int reg = 0; reg < 16; ++reg) {
      const int kvl = (reg & 3) + 8 * (reg >> 2) + 4 * hi;
      if (kv0 + kvl > qg) s0[reg] = -1e30f;
      if (kv0 + 32 + kvl > qg) s1[reg] = -1e30f;
    }
  }
  // p = exp2(s) directly (no max subtraction)
#pragma unroll
  for (int i = 0; i < 16; ++i) s0[i] = __builtin_amdgcn_exp2f(s0[i]);
#pragma unroll
  for (int i = 0; i < 16; ++i) s1[i] = __builtin_amdgcn_exp2f(s1[i]);

  // PV: P repack (cvt_pk + permlane32_swap) -> B-frag; V from LDS as A-frag;
  // l-accumulation via ones-MFMA on the same B-frag.
#pragma unroll
  for (int ks = 0; ks < 4; ++ks) {
    unsigned pa, pb, pc, pd;
    if (ks < 2) {
      pa = cvt_pk_bf16(s0[ks * 8 + 0], s0[ks * 8 + 1]);
      pb = cvt_pk_bf16(s0[ks * 8 + 2], s0[ks * 8 + 3]);
      pc = cvt_pk_bf16(s0[ks * 8 + 4], s0[ks * 8 + 5]);
      pd = cvt_pk_bf16(s0[ks * 8 + 6], s0[ks * 8 + 7]);
    } else {
      pa = cvt_pk_bf16(s1[(ks - 2) * 8 + 0], s1[(ks - 2) * 8 + 1]);
      pb = cvt_pk_bf16(s1[(ks - 2) * 8 + 2], s1[(ks - 2) * 8 + 3]);
      pc = cvt_pk_bf16(s1[(ks - 2) * 8 + 4], s1[(ks - 2) * 8 + 5]);
      pd = cvt_pk_bf16(s1[(ks - 2) * 8 + 6], s1[(ks - 2) * 8 + 7]);
    }
    asm volatile("v_permlane32_swap_b32 %0, %1" : "+v"(pa), "+v"(pc));
    asm volatile("v_permlane32_swap_b32 %0, %1" : "+v"(pb), "+v"(pd));
    union { unsigned u[4]; bf16x8 v; } pf;
    pf.u[0] = pa; pf.u[1] = pb; pf.u[2] = pc; pf.u[3] = pd;
    const int vb = ((ks * 2 + hi) ^ fx) * 8;
    bf16x8 v0 = *(const bf16x8*)&vsb[r0 * 64 + vb];
    bf16x8 v1 = *(const bf16x8*)&vsb[r1 * 64 + vb];
    o0 = __builtin_amdgcn_mfma_f32_32x32x16_bf16(v0, pf.v, o0, 0, 0, 0);
    o1 = __builtin_amdgcn_mfma_f32_32x32x16_bf16(v1, pf.v, o1, 0, 0, 0);
    accl = __builtin_amdgcn_mfma_f32_32x32x16_bf16(ones, pf.v, accl, 0, 0, 0);
  }
}

__device__ __forceinline__ void attn_epilogue(
    __bf16* __restrict__ vals, int bh, int q0w, int lq, int hi,
    const f32x16& o0, const f32x16& o1, float l) {
  const float inv = 1.f / l;
  unsigned* outp = (unsigned*)(vals + ((size_t)bh * 2048 + q0w + lq) * 64);
#pragma unroll
  for (int n = 0; n < 2; ++n) {
#pragma unroll
    for (int g = 0; g < 2; ++g) {
      const float e0 = (n ? o1[g * 8 + 0] : o0[g * 8 + 0]) * inv;
      const float e1 = (n ? o1[g * 8 + 1] : o0[g * 8 + 1]) * inv;
      const float e2 = (n ? o1[g * 8 + 2] : o0[g * 8 + 2]) * inv;
      const float e3 = (n ? o1[g * 8 + 3] : o0[g * 8 + 3]) * inv;
      const float e4 = (n ? o1[g * 8 + 4] : o0[g * 8 + 4]) * inv;
      const float e5 = (n ? o1[g * 8 + 5] : o0[g * 8 + 5]) * inv;
      const float e6 = (n ? o1[g * 8 + 6] : o0[g * 8 + 6]) * inv;
      const float e7 = (n ? o1[g * 8 + 7] : o0[g * 8 + 7]) * inv;
      unsigned a = cvt_pk_bf16(e0, e1);
      unsigned a2 = cvt_pk_bf16(e2, e3);
      unsigned b = cvt_pk_bf16(e4, e5);
      unsigned b2 = cvt_pk_bf16(e6, e7);
      asm volatile("v_permlane32_swap_b32 %0, %1" : "+v"(a), "+v"(b));
      asm volatile("v_permlane32_swap_b32 %0, %1" : "+v"(a2), "+v"(b2));
      int4 st = {(int)a, (int)a2, (int)b, (int)b2};
      *(int4*)&outp[(n * 32 + g * 16 + hi * 8) >> 1] = st;
    }
  }
}

__global__ __launch_bounds__(256) void attn_kernel(
    const __bf16* __restrict__ Q, const __bf16* __restrict__ K,
    const __bf16* __restrict__ Vt, __bf16* __restrict__ vals) {
  __shared__ __bf16 Ks[2][4096];
  __shared__ __bf16 Vs[2][4096];
  const int tid = threadIdx.x;
  const int wave = tid >> 6, lane = tid & 63;
  const int lq = lane & 31, hi = lane >> 5;

  const int wg = blockIdx.x + (blockIdx.y << 3);  // grid (8, 128) -> 0..1023
  const int wgid = (wg & 7) * 128 + (wg >> 3);    // bijective (1024 % 8 == 0)
  const int local = wgid & 127;
  const int bh = (wgid >> 7) * 8 + (local & 7);
  const int qc = 15 - (local >> 3);               // chunk 15 dispatched first
  const int q0w = qc * 128 + wave * 32;
  const int nt = 2 * qc + 2;

  bf16x8 qf[4];
  {
    const __bf16* qp = Q + ((size_t)bh * 2048 + q0w + lq) * 64 + hi * 8;
#pragma unroll
    for (int ds = 0; ds < 4; ++ds) qf[ds] = *(const bf16x8*)(qp + ds * 16);
  }

  f32x16 o0, o1, zz, accl;
#pragma unroll
  for (int i = 0; i < 16; ++i) { o0[i] = 0.f; o1[i] = 0.f; zz[i] = 0.f; accl[i] = 0.f; }
  bf16x8 ones;
#pragma unroll
  for (int i = 0; i < 8; ++i) ones[i] = (__bf16)1.0f;

  const int sr = tid >> 3, sb_ = tid & 7;
  const int sc = (sb_ ^ ((sr & 7) ^ ((sr >> 3) << 1))) * 8;
  const __bf16* Kg0 = K + ((size_t)bh * 2048 + sr) * 64 + sc;
  const __bf16* Kg1 = Kg0 + 32 * 64;
  const __bf16* Vg0 = Vt + ((size_t)bh * 64 + sr) * 2048 + sc;
  const __bf16* Vg1 = Vg0 + 32 * 2048;
  __bf16* KsW = &Ks[0][0] + wave * 512;
  __bf16* VsW = &Vs[0][0] + wave * 512;

#define STAGE(buf, t)                                                   \
  gload_lds16(Kg0 + (size_t)(t) * 4096, KsW + (buf) * 4096);            \
  gload_lds16(Kg1 + (size_t)(t) * 4096, KsW + (buf) * 4096 + 2048);     \
  gload_lds16(Vg0 + (t) * 64, VsW + (buf) * 4096);                      \
  gload_lds16(Vg1 + (t) * 64, VsW + (buf) * 4096 + 2048);

  STAGE(0, 0);
  __syncthreads();

  for (int t = 0; t < nt; ++t) {
    const int cur = t & 1;
    if (t + 1 < nt) { STAGE(cur ^ 1, t + 1); }
    attn_tile(&Ks[cur][0], &Vs[cur][0], qf, zz, ones, t * 64, q0w, lq, hi,
              o0, o1, accl);
    __syncthreads();
  }
#undef STAGE

  attn_epilogue(vals, bh, q0w, lq, hi, o0, o1, accl[0]);
}

// ---------------------------------------------------------------- launch
extern "C" void kernel_launch(void* const* d_in, const int* in_sizes, int n_in,
                              void* d_out, int out_size, void* d_ws, size_t ws_size,
                              hipStream_t stream) {
  const float* x = (const float*)d_in[0];
  const float* Wqkv = (const float*)d_in[1];
  const float* bqkv = (const float*)d_in[2];
  const float* Wo = (const float*)d_in[3];
  const float* bo = (const float*)d_in[4];
  float* out = (float*)d_out;
  char* ws = (char*)d_ws;

  // workspace layout (bytes)
  __bf16* xb  = (__bf16*)(ws);                 // 16 MB (x bf16; reused as vals)
  __bf16* Wqt = (__bf16*)(ws + 16777216);      // 6 MB  (W_qkv^T bf16 [3072][1024])
  __bf16* Wot = (__bf16*)(ws + 23068672);      // 2 MB  (W_o^T bf16 [1024][1024])
  __bf16* Qb  = (__bf16*)(ws + 25165824);      // 16 MB ([BH, S, 64], pre-scaled)
  __bf16* Kb  = (__bf16*)(ws + 41943040);      // 16 MB ([BH, S, 64])
  __bf16* Vtb = (__bf16*)(ws + 58720256);      // 16 MB ([BH, 64, S])
  __bf16* vals = xb;                           // attention output (scrambled matrix)

  fused_cvt_kernel<<<8192, 256, 0, stream>>>(x, xb, Wqkv, Wqt, Wo, Wot);
  gemm_qkv<<<768, 512, 0, stream>>>(xb, Wqt, bqkv, Qb, Kb, Vtb);
  attn_kernel<<<dim3(8, 128), 256, 0, stream>>>(Qb, Kb, Vtb, vals);
  gemm_o<<<512, 512, 0, stream>>>(vals, Wot, bo, out);
}

// Round 19
// 150.616 us; speedup vs baseline: 1.0464x; 1.0464x over previous
//
#include <hip/hip_runtime.h>
#include <hip/hip_bf16.h>
#include <stdint.h>

// MultiHeadAttention fused forward, MI355X/gfx950.
// B=4, S=2048, H=16, hd=64, D=1024. fp32 in/out, bf16 MFMA internally.
// R18 = R16 configuration (best measured: 151.0 us).

typedef __attribute__((ext_vector_type(8))) __bf16 bf16x8;
typedef __attribute__((ext_vector_type(4))) float f32x4;
typedef __attribute__((ext_vector_type(16))) float f32x16;

#define AS_G __attribute__((address_space(1)))
#define AS_L __attribute__((address_space(3)))

__device__ __forceinline__ void gload_lds16(const void* g, void* s) {
  __builtin_amdgcn_global_load_lds((const AS_G void*)g, (AS_L void*)s, 16, 0, 0);
}

__device__ __forceinline__ unsigned cvt_pk_bf16(float lo, float hi) {
  unsigned r;
  asm("v_cvt_pk_bf16_f32 %0, %1, %2" : "=v"(r) : "v"(lo), "v"(hi));
  return r;
}

// ---------------------------------------------------------------- fused cvt
// One launch: blocks [0,4096) x->bf16 ; [4096,7168) Wqkv^T ; [7168,8192) Wo^T
__device__ __forceinline__ void cvt_T_body(const float* __restrict__ in,
                                           __bf16* __restrict__ out,
                                           int K, int N, int bx, int by,
                                           float (*tile)[33]) {
  int tx = threadIdx.x & 31, ty = threadIdx.x >> 5;  // 32 x 8
#pragma unroll
  for (int i = 0; i < 32; i += 8)
    tile[ty + i][tx] = in[(size_t)(by * 32 + ty + i) * N + bx * 32 + tx];
  __syncthreads();
#pragma unroll
  for (int i = 0; i < 32; i += 8)
    out[(size_t)(bx * 32 + ty + i) * K + by * 32 + tx] = (__bf16)tile[tx][ty + i];
}

__global__ void fused_cvt_kernel(const float* __restrict__ x,
                                 __bf16* __restrict__ xb,
                                 const float* __restrict__ Wqkv,
                                 __bf16* __restrict__ Wqt,
                                 const float* __restrict__ Wo,
                                 __bf16* __restrict__ Wot) {
  __shared__ float tile[32][33];
  const int bid = blockIdx.x;
  if (bid < 4096) {
    const int i = bid * 256 + threadIdx.x;  // n8 = 1048576
    float4 a = ((const float4*)x)[i * 2];
    float4 b = ((const float4*)x)[i * 2 + 1];
    union { __bf16 h[8]; int4 v; } u;
    u.h[0] = (__bf16)a.x; u.h[1] = (__bf16)a.y; u.h[2] = (__bf16)a.z; u.h[3] = (__bf16)a.w;
    u.h[4] = (__bf16)b.x; u.h[5] = (__bf16)b.y; u.h[6] = (__bf16)b.z; u.h[7] = (__bf16)b.w;
    ((int4*)xb)[i] = u.v;
  } else if (bid < 7168) {
    const int t = bid - 4096;               // 96 x 32
    cvt_T_body(Wqkv, Wqt, 1024, 3072, t % 96, t / 96, tile);
  } else {
    const int t = bid - 7168;               // 32 x 32
    cvt_T_body(Wo, Wot, 1024, 1024, t % 32, t / 32, tile);
  }
}

// ---------------------------------------------------------------- GEMM 256x128
// Proven structure (63.3us @ grid 768): single barrier per phase, 3-buffer
// rotation, 2 blocks/CU. BM=256, BN=128, K-chunk=32, 8 waves (4M x 2N).
// LDS 72KB: A 3x16KB @0, B 3x8KB @49152.
// Per phase p (c = p%3):
//   { s_barrier; 8 ds_read (buf c); issue 3 gloads (chunk p+2 -> buf (p+2)%3);
//     lgkmcnt(0); 16 MFMA (setprio); vmcnt(3) }
// Ledger: WAR -- stage(p) writes buf (p-1)%3; its readers retired at
// lgkm0(p-1) before any wave reaches barrier(p). RAW -- vmcnt(3) at p-1
// retires chunk p's stage; barrier(p) orders it before the reads.
// MODE 0: QKV scatter epilogue, grid 768. MODE 1: fp32 out + bias, grid 256.
template <int MODE>
__global__ __launch_bounds__(512, 4) void gemm256(
    const __bf16* __restrict__ A, const __bf16* __restrict__ Bt,
    const float* __restrict__ bias,
    __bf16* __restrict__ Qb, __bf16* __restrict__ Kb, __bf16* __restrict__ Vtb,
    float* __restrict__ Out) {
  __shared__ char lds[73728];   // A: 3 x 16KB @0, B: 3 x 8KB @49152
  const int tid = threadIdx.x;
  const int wv = tid >> 6, lane = tid & 63;
  const int lhi = lane >> 4, llo = lane & 15;
  const int wm = wv >> 1, wn = wv & 1;   // 4M x 2N

  // XCD-chunked (grid % 8 == 0), m-fastest: per-XCD A-set = 4 tiles (2MB)
  const int wg = blockIdx.x;
  const int xcd = wg & 7, local = wg >> 3;
  const int m0 = (xcd * 4 + (local & 3)) * 256;
  const int n0 = (local >> 2) * 128;

  // staging sources (inverse-swizzled, rule 21)
  int SA[2], SB;
#pragma unroll
  for (int j = 0; j < 2; ++j) {
    const int idx = j * 512 + tid;
    const int v = idx >> 3, wl = idx & 7;
    const int wg_ = wl ^ (v & 7);
    SA[j] = ((v << 1) | (wg_ >> 2)) * 1024 + (wg_ & 3) * 8;
  }
  {
    const int v = tid >> 3, wl = tid & 7;
    const int wg_ = wl ^ (v & 7);
    SB = ((v << 1) | (wg_ >> 2)) * 1024 + (wg_ & 3) * 8;
  }
  const __bf16* Asrc = A + (size_t)m0 * 1024;
  const __bf16* Bsrc = Bt + (size_t)n0 * 1024;
  const int wvb = wv * 1024;  // wave-uniform LDS line offset

  // stage one region: K-chunk kc (32 wide) into buffer b (3 gloads)
#define STAGE_R(b, kc)                                                      \
  gload_lds16(Asrc + SA[0] + (kc) * 32, &lds[(b) * 16384 + wvb]);           \
  gload_lds16(Asrc + SA[1] + (kc) * 32, &lds[(b) * 16384 + 8192 + wvb]);    \
  gload_lds16(Bsrc + SB + (kc) * 32,    &lds[49152 + (b) * 8192 + wvb]);

  f32x4 acc[4][4];
#pragma unroll
  for (int mi = 0; mi < 4; ++mi)
#pragma unroll
    for (int nj = 0; nj < 4; ++nj) acc[mi][nj] = (f32x4){0.f, 0.f, 0.f, 0.f};

  auto aoff = [&](int b, int f) {
    const int r = wm * 64 + f * 16 + llo;
    const int v = r >> 1;
    const int w = ((r & 1) << 2) | lhi;
    return b * 16384 + v * 128 + ((w ^ (v & 7)) << 4);
  };
  auto boff = [&](int b, int f2) {
    const int r = wn * 64 + f2 * 16 + llo;
    const int v = r >> 1;
    const int w = ((r & 1) << 2) | lhi;
    return 49152 + b * 8192 + v * 128 + ((w ^ (v & 7)) << 4);
  };

  auto PH = [&](int c, int sb, int kc) {
    __builtin_amdgcn_s_barrier();                       // single barrier
    __builtin_amdgcn_sched_barrier(0);
    bf16x8 fa[4], fb[4];
#pragma unroll
    for (int f = 0; f < 4; ++f) fa[f] = *(const bf16x8*)&lds[aoff(c, f)];
#pragma unroll
    for (int f2 = 0; f2 < 4; ++f2) fb[f2] = *(const bf16x8*)&lds[boff(c, f2)];
    STAGE_R(sb, kc);
    __builtin_amdgcn_sched_barrier(0);
    asm volatile("s_waitcnt lgkmcnt(0)" ::: "memory");
    __builtin_amdgcn_sched_barrier(0);
    __builtin_amdgcn_s_setprio(1);
#pragma unroll
    for (int mi = 0; mi < 4; ++mi)
#pragma unroll
      for (int nj = 0; nj < 4; ++nj)
        acc[mi][nj] = __builtin_amdgcn_mfma_f32_16x16x32_bf16(fa[mi], fb[nj],
                                                              acc[mi][nj], 0, 0, 0);
    __builtin_amdgcn_s_setprio(0);
    __builtin_amdgcn_sched_barrier(0);
    asm volatile("s_waitcnt vmcnt(3)" ::: "memory");
  };

  // prologue: chunk0 -> buf0, chunk1 -> buf1; retire chunk0 before phase 0
  STAGE_R(0, 0);
  STAGE_R(1, 1);
  __builtin_amdgcn_sched_barrier(0);
  asm volatile("s_waitcnt vmcnt(3)" ::: "memory");

  {
    int c = 0, sb = 2;
    for (int p = 0; p < 32; ++p) {
      const int kc = (p + 2) & 31;   // wrap stages dead buffers (harmless)
      PH(c, sb, kc);
      if (++c == 3) c = 0;
      if (++sb == 3) sb = 0;
    }
  }
#undef STAGE_R

  // ---------------- epilogue
#pragma unroll
  for (int nj = 0; nj < 4; ++nj) {
    const int col = n0 + wn * 64 + nj * 16 + llo;
    const float bv = bias[col];
    if (MODE == 0) {
      const int h = col / 192, rem = col % 192;
#pragma unroll
      for (int mi = 0; mi < 4; ++mi) {
        const int row0 = m0 + wm * 64 + mi * 16 + lhi * 4;
        const int b = row0 >> 11;
        const int s0 = row0 & 2047;
        const int bh = b * 16 + h;
        f32x4 v = acc[mi][nj];
        if (rem < 64) {
          // Q pre-scaled by (1/sqrt(64)) * log2(e) for exp2-domain softmax
#pragma unroll
          for (int r = 0; r < 4; ++r)
            Qb[((size_t)bh * 2048 + s0 + r) * 64 + rem] =
                (__bf16)((v[r] + bv) * 0.18033688011112042f);
        } else if (rem < 128) {
#pragma unroll
          for (int r = 0; r < 4; ++r)
            Kb[((size_t)bh * 2048 + s0 + r) * 64 + (rem - 64)] = (__bf16)(v[r] + bv);
        } else {
          union { __bf16 h4[4]; int2 v2; } uq;
#pragma unroll
          for (int r = 0; r < 4; ++r) uq.h4[r] = (__bf16)(v[r] + bv);
          *(int2*)&Vtb[((size_t)bh * 64 + (rem - 128)) * 2048 + s0] = uq.v2;
        }
      }
    } else {
#pragma unroll
      for (int mi = 0; mi < 4; ++mi) {
        const int row0 = m0 + wm * 64 + mi * 16 + lhi * 4;
        f32x4 v = acc[mi][nj];
#pragma unroll
        for (int r = 0; r < 4; ++r)
          Out[(size_t)(row0 + r) * 1024 + col] = v[r] + bv;
      }
    }
  }
}

// ---------------------------------------------------------------- attention
// 4 waves x 32 q-rows = 128-row chunk per block; 1024 blocks (4/CU).
// Swapped QK^T / swapped PV; NO-MAX exp2 softmax (bounded logits; exact by
// shift invariance). zz as QK MFMA C-operand. l accumulated via MFMA with a
// ones A-operand: accl = mfma(ones, P^T, accl) -> D[row][q] = sum_k P[q][k]
// (row-independent); lane's col = its q-row, so l = accl[0] at the end.

__device__ __forceinline__ void attn_tile(
    const __bf16* __restrict__ ksb, const __bf16* __restrict__ vsb,
    const bf16x8* qf, const f32x16& zz, const bf16x8& ones,
    int kv0, int q0w, int lq, int hi,
    f32x16& o0, f32x16& o1, f32x16& accl) {
  const int r0 = lq, r1 = 32 + lq;
  const int fx = (lq & 7) ^ ((lq >> 3) << 1);  // matches staging swizzle
  f32x16 s0, s1;
  __builtin_amdgcn_s_setprio(1);
  {
    const int bb = (hi ^ fx) * 8;
    bf16x8 k0 = *(const bf16x8*)&ksb[r0 * 64 + bb];
    bf16x8 k1 = *(const bf16x8*)&ksb[r1 * 64 + bb];
    s0 = __builtin_amdgcn_mfma_f32_32x32x16_bf16(k0, qf[0], zz, 0, 0, 0);
    s1 = __builtin_amdgcn_mfma_f32_32x32x16_bf16(k1, qf[0], zz, 0, 0, 0);
  }
#pragma unroll
  for (int ds = 1; ds < 4; ++ds) {
    const int bb = ((ds * 2 + hi) ^ fx) * 8;
    bf16x8 k0 = *(const bf16x8*)&ksb[r0 * 64 + bb];
    bf16x8 k1 = *(const bf16x8*)&ksb[r1 * 64 + bb];
    s0 = __builtin_amdgcn_mfma_f32_32x32x16_bf16(k0, qf[ds], s0, 0, 0, 0);
    s1 = __builtin_amdgcn_mfma_f32_32x32x16_bf16(k1, qf[ds], s1, 0, 0, 0);
  }
  __builtin_amdgcn_s_setprio(0);

  const int qg = q0w + lq;
  if (kv0 + 63 > q0w) {  // causal mask (log2 domain; -1e30 -> exp2 = 0)
#pragma unroll
    for (int reg = 0; reg < 16; ++reg) {
      const int kvl = (reg & 3) + 8 * (reg >> 2) + 4 * hi;
      if (kv0 + kvl > qg) s0[reg] = -1e30f;
      if (kv0 + 32 + kvl > qg) s1[reg] = -1e30f;
    }
  }
  // p = exp2(s) directly (no max subtraction)
#pragma unroll
  for (int i = 0; i < 16; ++i) s0[i] = __builtin_amdgcn_exp2f(s0[i]);
#pragma unroll
  for (int i = 0; i < 16; ++i) s1[i] = __builtin_amdgcn_exp2f(s1[i]);

  // PV: P repack (cvt_pk + permlane32_swap) -> B-frag; V from LDS as A-frag;
  // l-accumulation via ones-MFMA on the same B-frag.
#pragma unroll
  for (int ks = 0; ks < 4; ++ks) {
    unsigned pa, pb, pc, pd;
    if (ks < 2) {
      pa = cvt_pk_bf16(s0[ks * 8 + 0], s0[ks * 8 + 1]);
      pb = cvt_pk_bf16(s0[ks * 8 + 2], s0[ks * 8 + 3]);
      pc = cvt_pk_bf16(s0[ks * 8 + 4], s0[ks * 8 + 5]);
      pd = cvt_pk_bf16(s0[ks * 8 + 6], s0[ks * 8 + 7]);
    } else {
      pa = cvt_pk_bf16(s1[(ks - 2) * 8 + 0], s1[(ks - 2) * 8 + 1]);
      pb = cvt_pk_bf16(s1[(ks - 2) * 8 + 2], s1[(ks - 2) * 8 + 3]);
      pc = cvt_pk_bf16(s1[(ks - 2) * 8 + 4], s1[(ks - 2) * 8 + 5]);
      pd = cvt_pk_bf16(s1[(ks - 2) * 8 + 6], s1[(ks - 2) * 8 + 7]);
    }
    asm volatile("v_permlane32_swap_b32 %0, %1" : "+v"(pa), "+v"(pc));
    asm volatile("v_permlane32_swap_b32 %0, %1" : "+v"(pb), "+v"(pd));
    union { unsigned u[4]; bf16x8 v; } pf;
    pf.u[0] = pa; pf.u[1] = pb; pf.u[2] = pc; pf.u[3] = pd;
    const int vb = ((ks * 2 + hi) ^ fx) * 8;
    bf16x8 v0 = *(const bf16x8*)&vsb[r0 * 64 + vb];
    bf16x8 v1 = *(const bf16x8*)&vsb[r1 * 64 + vb];
    o0 = __builtin_amdgcn_mfma_f32_32x32x16_bf16(v0, pf.v, o0, 0, 0, 0);
    o1 = __builtin_amdgcn_mfma_f32_32x32x16_bf16(v1, pf.v, o1, 0, 0, 0);
    accl = __builtin_amdgcn_mfma_f32_32x32x16_bf16(ones, pf.v, accl, 0, 0, 0);
  }
}

__device__ __forceinline__ void attn_epilogue(
    __bf16* __restrict__ vals, int bh, int q0w, int lq, int hi,
    const f32x16& o0, const f32x16& o1, float l) {
  const float inv = 1.f / l;
  unsigned* outp = (unsigned*)(vals + ((size_t)bh * 2048 + q0w + lq) * 64);
#pragma unroll
  for (int n = 0; n < 2; ++n) {
#pragma unroll
    for (int g = 0; g < 2; ++g) {
      const float e0 = (n ? o1[g * 8 + 0] : o0[g * 8 + 0]) * inv;
      const float e1 = (n ? o1[g * 8 + 1] : o0[g * 8 + 1]) * inv;
      const float e2 = (n ? o1[g * 8 + 2] : o0[g * 8 + 2]) * inv;
      const float e3 = (n ? o1[g * 8 + 3] : o0[g * 8 + 3]) * inv;
      const float e4 = (n ? o1[g * 8 + 4] : o0[g * 8 + 4]) * inv;
      const float e5 = (n ? o1[g * 8 + 5] : o0[g * 8 + 5]) * inv;
      const float e6 = (n ? o1[g * 8 + 6] : o0[g * 8 + 6]) * inv;
      const float e7 = (n ? o1[g * 8 + 7] : o0[g * 8 + 7]) * inv;
      unsigned a = cvt_pk_bf16(e0, e1);
      unsigned a2 = cvt_pk_bf16(e2, e3);
      unsigned b = cvt_pk_bf16(e4, e5);
      unsigned b2 = cvt_pk_bf16(e6, e7);
      asm volatile("v_permlane32_swap_b32 %0, %1" : "+v"(a), "+v"(b));
      asm volatile("v_permlane32_swap_b32 %0, %1" : "+v"(a2), "+v"(b2));
      int4 st = {(int)a, (int)a2, (int)b, (int)b2};
      *(int4*)&outp[(n * 32 + g * 16 + hi * 8) >> 1] = st;
    }
  }
}

__global__ __launch_bounds__(256) void attn_kernel(
    const __bf16* __restrict__ Q, const __bf16* __restrict__ K,
    const __bf16* __restrict__ Vt, __bf16* __restrict__ vals) {
  __shared__ __bf16 Ks[2][4096];
  __shared__ __bf16 Vs[2][4096];
  const int tid = threadIdx.x;
  const int wave = tid >> 6, lane = tid & 63;
  const int lq = lane & 31, hi = lane >> 5;

  const int wg = blockIdx.x + (blockIdx.y << 3);  // grid (8, 128) -> 0..1023
  const int wgid = (wg & 7) * 128 + (wg >> 3);    // bijective (1024 % 8 == 0)
  const int local = wgid & 127;
  const int bh = (wgid >> 7) * 8 + (local & 7);
  const int qc = 15 - (local >> 3);               // chunk 15 dispatched first
  const int q0w = qc * 128 + wave * 32;
  const int nt = 2 * qc + 2;

  bf16x8 qf[4];
  {
    const __bf16* qp = Q + ((size_t)bh * 2048 + q0w + lq) * 64 + hi * 8;
#pragma unroll
    for (int ds = 0; ds < 4; ++ds) qf[ds] = *(const bf16x8*)(qp + ds * 16);
  }

  f32x16 o0, o1, zz, accl;
#pragma unroll
  for (int i = 0; i < 16; ++i) { o0[i] = 0.f; o1[i] = 0.f; zz[i] = 0.f; accl[i] = 0.f; }
  bf16x8 ones;
#pragma unroll
  for (int i = 0; i < 8; ++i) ones[i] = (__bf16)1.0f;

  const int sr = tid >> 3, sb_ = tid & 7;
  const int sc = (sb_ ^ ((sr & 7) ^ ((sr >> 3) << 1))) * 8;
  const __bf16* Kg0 = K + ((size_t)bh * 2048 + sr) * 64 + sc;
  const __bf16* Kg1 = Kg0 + 32 * 64;
  const __bf16* Vg0 = Vt + ((size_t)bh * 64 + sr) * 2048 + sc;
  const __bf16* Vg1 = Vg0 + 32 * 2048;
  __bf16* KsW = &Ks[0][0] + wave * 512;
  __bf16* VsW = &Vs[0][0] + wave * 512;

#define STAGE(buf, t)                                                   \
  gload_lds16(Kg0 + (size_t)(t) * 4096, KsW + (buf) * 4096);            \
  gload_lds16(Kg1 + (size_t)(t) * 4096, KsW + (buf) * 4096 + 2048);     \
  gload_lds16(Vg0 + (t) * 64, VsW + (buf) * 4096);                      \
  gload_lds16(Vg1 + (t) * 64, VsW + (buf) * 4096 + 2048);

  STAGE(0, 0);
  __syncthreads();

  for (int t = 0; t < nt; ++t) {
    const int cur = t & 1;
    if (t + 1 < nt) { STAGE(cur ^ 1, t + 1); }
    attn_tile(&Ks[cur][0], &Vs[cur][0], qf, zz, ones, t * 64, q0w, lq, hi,
              o0, o1, accl);
    __syncthreads();
  }
#undef STAGE

  attn_epilogue(vals, bh, q0w, lq, hi, o0, o1, accl[0]);
}

// ---------------------------------------------------------------- launch
extern "C" void kernel_launch(void* const* d_in, const int* in_sizes, int n_in,
                              void* d_out, int out_size, void* d_ws, size_t ws_size,
                              hipStream_t stream) {
  const float* x = (const float*)d_in[0];
  const float* Wqkv = (const float*)d_in[1];
  const float* bqkv = (const float*)d_in[2];
  const float* Wo = (const float*)d_in[3];
  const float* bo = (const float*)d_in[4];
  float* out = (float*)d_out;
  char* ws = (char*)d_ws;

  // workspace layout (bytes)
  __bf16* xb  = (__bf16*)(ws);                 // 16 MB (x bf16; reused as vals)
  __bf16* Wqt = (__bf16*)(ws + 16777216);      // 6 MB  (W_qkv^T bf16 [3072][1024])
  __bf16* Wot = (__bf16*)(ws + 23068672);      // 2 MB  (W_o^T bf16 [1024][1024])
  __bf16* Qb  = (__bf16*)(ws + 25165824);      // 16 MB ([BH, S, 64], pre-scaled)
  __bf16* Kb  = (__bf16*)(ws + 41943040);      // 16 MB ([BH, S, 64])
  __bf16* Vtb = (__bf16*)(ws + 58720256);      // 16 MB ([BH, 64, S])
  __bf16* vals = xb;                           // attention output (scrambled matrix)

  fused_cvt_kernel<<<8192, 256, 0, stream>>>(x, xb, Wqkv, Wqt, Wo, Wot);
  gemm256<0><<<768, 512, 0, stream>>>(xb, Wqt, bqkv, Qb, Kb, Vtb, nullptr);
  attn_kernel<<<dim3(8, 128), 256, 0, stream>>>(Qb, Kb, Vtb, vals);
  gemm256<1><<<256, 512, 0, stream>>>(vals, Wot, bo, nullptr, nullptr, nullptr, out);
}